// Round 11
// baseline (761.863 us; speedup 1.0000x reference)
//
#include <hip/hip_runtime.h>
#include <hip/hip_cooperative_groups.h>
#include <cstdint>
#include <cstddef>

namespace cg = cooperative_groups;

#define FEAT 128
#define FOUT 40
constexpr float BN_EPS = 1e-5f;

typedef __attribute__((ext_vector_type(8))) short bf16x8;
typedef __attribute__((ext_vector_type(4))) float f32x4;

__device__ __forceinline__ unsigned short f2bf(float f) {
    unsigned u = __float_as_uint(f);
    u += 0x7FFFu + ((u >> 16) & 1u);
    return (unsigned short)(u >> 16);
}
__device__ __forceinline__ float bflo(unsigned u) { return __uint_as_float(u << 16); }
__device__ __forceinline__ float bfhi(unsigned u) { return __uint_as_float(u & 0xFFFF0000u); }
__device__ __forceinline__ unsigned packbf2(float a, float b) {
    return (unsigned)f2bf(a) | ((unsigned)f2bf(b) << 16);
}

// ---------------- CSR build: single cooperative kernel ----------------
// phases: zero cnt -> count -> scan1 (chunk sums) -> scan2 (chunk prefix) ->
//         scan3 (+cursor+dinv) -> fill

__global__ __launch_bounds__(256) void csr_build_k(const int* __restrict__ src, const int* __restrict__ dst,
                                                   int* __restrict__ cnt, int* __restrict__ offs,
                                                   int* __restrict__ cursor, float* __restrict__ dinv,
                                                   int* __restrict__ csr, int* __restrict__ bsum,
                                                   int* __restrict__ boff, int n, int E, int nb) {
    cg::grid_group grid = cg::this_grid();
    __shared__ int sh[256];
    const int t = threadIdx.x;
    const int gtid = blockIdx.x * 256 + t;
    const int gstride = gridDim.x * 256;

    // P0: zero cnt
    for (int i = gtid; i < n; i += gstride) cnt[i] = 0;
    grid.sync();

    // P1: count
    for (int e = gtid; e < E; e += gstride) atomicAdd(&cnt[dst[e]], 1);
    grid.sync();

    // P2: per-chunk (1024 elems) sums
    for (int chunk = blockIdx.x; chunk < nb; chunk += gridDim.x) {
        int base = chunk * 1024;
        int s = 0;
#pragma unroll
        for (int j = 0; j < 4; ++j) {
            int idx = base + t * 4 + j;
            if (idx < n) s += cnt[idx];
        }
        sh[t] = s;
        __syncthreads();
        for (int o = 128; o > 0; o >>= 1) {
            if (t < o) sh[t] += sh[t + o];
            __syncthreads();
        }
        if (t == 0) bsum[chunk] = sh[0];
        __syncthreads();
    }
    grid.sync();

    // P3: chunk prefix (block 0)
    if (blockIdx.x == 0) {
        if (nb <= 256) {
            int v = (t < nb) ? bsum[t] : 0;
            sh[t] = v;
            __syncthreads();
            for (int o = 1; o < 256; o <<= 1) {
                int x = (t >= o) ? sh[t - o] : 0;
                __syncthreads();
                sh[t] += x;
                __syncthreads();
            }
            if (t < nb) boff[t] = sh[t] - v;
            if (t == 0) offs[n] = E;
        } else if (t == 0) {
            int run = 0;
            for (int i = 0; i < nb; ++i) { boff[i] = run; run += bsum[i]; }
            offs[n] = E;
        }
    }
    grid.sync();

    // P4: within-chunk scan + offs + cursor + dinv
    for (int chunk = blockIdx.x; chunk < nb; chunk += gridDim.x) {
        int base = chunk * 1024;
        int c[4];
        int s = 0;
#pragma unroll
        for (int j = 0; j < 4; ++j) {
            int idx = base + t * 4 + j;
            c[j] = (idx < n) ? cnt[idx] : 0;
            s += c[j];
        }
        sh[t] = s;
        __syncthreads();
        for (int o = 1; o < 256; o <<= 1) {
            int v = (t >= o) ? sh[t - o] : 0;
            __syncthreads();
            sh[t] += v;
            __syncthreads();
        }
        int g = boff[chunk] + sh[t] - s;
#pragma unroll
        for (int j = 0; j < 4; ++j) {
            int idx = base + t * 4 + j;
            if (idx < n) {
                offs[idx] = g;
                cursor[idx] = g;
                dinv[idx] = rsqrtf((float)(c[j] + 1));
            }
            g += c[j];
        }
        __syncthreads();
    }
    grid.sync();

    // P5: fill
    for (int e = gtid; e < E; e += gstride) {
        int d = dst[e];
        int p = atomicAdd(&cursor[d], 1);
        csr[p] = src[e];
    }
}

// ---------------- weight pack (+ zero both BN sums buffers) ----------------

__global__ __launch_bounds__(256) void castW_k(const float* __restrict__ W1, const float* __restrict__ W2,
                                               const float* __restrict__ W3,
                                               unsigned short* __restrict__ Wt1, unsigned short* __restrict__ Wt2,
                                               unsigned short* __restrict__ Wt3,
                                               float* __restrict__ sums1, float* __restrict__ sums2) {
    int tid = blockIdx.x * 256 + threadIdx.x;
    int stride = gridDim.x * 256;
    if (tid < 256) { sums1[tid] = 0.f; sums2[tid] = 0.f; }
    for (int i = tid; i < 4 * 4 * 128 * 8; i += stride) {
        int j = i & 7, c = (i >> 3) & 127, q = (i >> 10) & 3, kt = i >> 12;
        int k = kt * 32 + q * 8 + j;
        Wt1[i] = f2bf(W1[k * 128 + c]);
        Wt2[i] = f2bf(W2[k * 128 + c]);
    }
    for (int i = tid; i < 4 * 4 * 48 * 8; i += stride) {
        int j = i & 7, rest = i >> 3;
        int c = rest % 48, kq = rest / 48;
        int q = kq & 3, kt = kq >> 2;
        int k = kt * 32 + q * 8 + j;
        Wt3[i] = (c < FOUT) ? f2bf(W3[k * FOUT + c]) : (unsigned short)0;
    }
}

// ---------------- MFMA GEMM 128x128, BN computed inline from raw sums ----------------

template <int SRC>
__global__ __launch_bounds__(256, 3) void gemm128_k(const void* __restrict__ srcp,
                                                    const unsigned short* __restrict__ Wt,
                                                    const float* __restrict__ sums,
                                                    const float* __restrict__ gam,
                                                    const float* __restrict__ bet,
                                                    float inv_n,
                                                    const float* __restrict__ dinv,
                                                    unsigned short* __restrict__ Hb,
                                                    int ntiles, int nreal) {
    __shared__ uint4 XsU[64 * 16];
    unsigned short* Xs = (unsigned short*)XsU;

    const int t = threadIdx.x;
    const int tc = t & 15;
    const int l = t & 63, w = t >> 6;
    const int wm = w >> 1, wn = w & 1;
    const int lr = l & 15, q = l >> 4;

    float sc[8], sh2[8];
    if (SRC == 1) {
#pragma unroll
        for (int j = 0; j < 8; ++j) {
            int f = tc * 8 + j;
            float mu = sums[f] * inv_n;
            float var = sums[128 + f] * inv_n - mu * mu;
            float rstd = rsqrtf(var + BN_EPS);
            float scv = gam[f] * rstd;
            sc[j] = scv;
            sh2[j] = bet[f] - mu * scv;
        }
    }

    bf16x8 Bf[4][4];
#pragma unroll
    for (int kt = 0; kt < 4; ++kt)
#pragma unroll
        for (int n = 0; n < 4; ++n) {
            int col = wn * 64 + n * 16 + lr;
            Bf[kt][n] = *(const bf16x8*)&((const uint4*)Wt)[(kt * 4 + q) * 128 + col];
        }

    for (int tile = blockIdx.x; tile < ntiles; tile += gridDim.x) {
        const int row0 = tile * 64;
        __syncthreads();
#pragma unroll
        for (int k2 = 0; k2 < 4; ++k2) {
            int row = (t >> 4) + k2 * 16;
            int grow = row0 + row;
            uint4 o;
            if (SRC == 0) {
                if (grow < nreal) {
                    const float4* xp = (const float4*)((const float*)srcp + (size_t)grow * FEAT + tc * 8);
                    float4 f0 = xp[0], f1 = xp[1];
                    o.x = packbf2(f0.x, f0.y); o.y = packbf2(f0.z, f0.w);
                    o.z = packbf2(f1.x, f1.y); o.w = packbf2(f1.z, f1.w);
                } else {
                    o.x = 0u; o.y = 0u; o.z = 0u; o.w = 0u;
                }
            } else {
                uint4 u = ((const uint4*)((const unsigned short*)srcp + (size_t)grow * FEAT))[tc];
                float v0 = fmaxf(fmaf(bflo(u.x), sc[0], sh2[0]), 0.f);
                float v1 = fmaxf(fmaf(bfhi(u.x), sc[1], sh2[1]), 0.f);
                float v2 = fmaxf(fmaf(bflo(u.y), sc[2], sh2[2]), 0.f);
                float v3 = fmaxf(fmaf(bfhi(u.y), sc[3], sh2[3]), 0.f);
                float v4 = fmaxf(fmaf(bflo(u.z), sc[4], sh2[4]), 0.f);
                float v5 = fmaxf(fmaf(bfhi(u.z), sc[5], sh2[5]), 0.f);
                float v6 = fmaxf(fmaf(bflo(u.w), sc[6], sh2[6]), 0.f);
                float v7 = fmaxf(fmaf(bfhi(u.w), sc[7], sh2[7]), 0.f);
                o.x = packbf2(v0, v1); o.y = packbf2(v2, v3);
                o.z = packbf2(v4, v5); o.w = packbf2(v6, v7);
            }
            XsU[row * 16 + (tc ^ (row & 7))] = o;
        }
        __syncthreads();

        f32x4 acc[2][4];
#pragma unroll
        for (int m = 0; m < 2; ++m)
#pragma unroll
            for (int n = 0; n < 4; ++n)
#pragma unroll
                for (int r2 = 0; r2 < 4; ++r2) acc[m][n][r2] = 0.f;

#pragma unroll
        for (int kt = 0; kt < 4; ++kt) {
            int rowA = wm * 32 + lr;
            bf16x8 A0 = *(const bf16x8*)&XsU[rowA * 16 + ((kt * 4 + q) ^ (rowA & 7))];
            int rowB = rowA + 16;
            bf16x8 A1 = *(const bf16x8*)&XsU[rowB * 16 + ((kt * 4 + q) ^ (rowB & 7))];
#pragma unroll
            for (int n = 0; n < 4; ++n) {
                acc[0][n] = __builtin_amdgcn_mfma_f32_16x16x32_bf16(A0, Bf[kt][n], acc[0][n], 0, 0, 0);
                acc[1][n] = __builtin_amdgcn_mfma_f32_16x16x32_bf16(A1, Bf[kt][n], acc[1][n], 0, 0, 0);
            }
        }
        __syncthreads();

#pragma unroll
        for (int m = 0; m < 2; ++m) {
            float dv[4];
#pragma unroll
            for (int r = 0; r < 4; ++r) dv[r] = dinv[row0 + wm * 32 + m * 16 + q * 4 + r];
#pragma unroll
            for (int n = 0; n < 4; ++n) {
                int col = wn * 64 + n * 16 + lr;
#pragma unroll
                for (int r = 0; r < 4; ++r) {
                    int row = wm * 32 + m * 16 + q * 4 + r;
                    Xs[row * 128 + (((col >> 3) ^ (row & 7)) << 3) + (col & 7)] = f2bf(acc[m][n][r] * dv[r]);
                }
            }
        }
        __syncthreads();
#pragma unroll
        for (int k2 = 0; k2 < 4; ++k2) {
            int row = (t >> 4) + k2 * 16;
            ((uint4*)&Hb[(size_t)(row0 + row) * FEAT])[tc] = XsU[row * 16 + (tc ^ (row & 7))];
        }
    }
}

// ---------------- MFMA GEMM 128x40 (padded to 48), BN inline ----------------

__global__ __launch_bounds__(256, 4) void gemm40_k(const unsigned short* __restrict__ srcp,
                                                   const unsigned short* __restrict__ Wt,
                                                   const float* __restrict__ sums,
                                                   const float* __restrict__ gam,
                                                   const float* __restrict__ bet,
                                                   float inv_n,
                                                   const float* __restrict__ dinv,
                                                   unsigned short* __restrict__ H3,
                                                   int ntiles) {
    __shared__ uint4 XsU[64 * 16];
    unsigned short* Xs = (unsigned short*)XsU;
    const int t = threadIdx.x, tc = t & 15;
    const int l = t & 63, w = t >> 6, lr = l & 15, q = l >> 4;

    float sc[8], sh2[8];
#pragma unroll
    for (int j = 0; j < 8; ++j) {
        int f = tc * 8 + j;
        float mu = sums[f] * inv_n;
        float var = sums[128 + f] * inv_n - mu * mu;
        float rstd = rsqrtf(var + BN_EPS);
        float scv = gam[f] * rstd;
        sc[j] = scv;
        sh2[j] = bet[f] - mu * scv;
    }

    bf16x8 Bf[4][3];
#pragma unroll
    for (int kt = 0; kt < 4; ++kt)
#pragma unroll
        for (int n = 0; n < 3; ++n)
            Bf[kt][n] = *(const bf16x8*)&((const uint4*)Wt)[(kt * 4 + q) * 48 + n * 16 + lr];

    for (int tile = blockIdx.x; tile < ntiles; tile += gridDim.x) {
        const int row0 = tile * 64;
        __syncthreads();
#pragma unroll
        for (int k2 = 0; k2 < 4; ++k2) {
            int row = (t >> 4) + k2 * 16;
            int grow = row0 + row;
            uint4 u = ((const uint4*)(srcp + (size_t)grow * FEAT))[tc];
            float v0 = fmaxf(fmaf(bflo(u.x), sc[0], sh2[0]), 0.f);
            float v1 = fmaxf(fmaf(bfhi(u.x), sc[1], sh2[1]), 0.f);
            float v2 = fmaxf(fmaf(bflo(u.y), sc[2], sh2[2]), 0.f);
            float v3 = fmaxf(fmaf(bfhi(u.y), sc[3], sh2[3]), 0.f);
            float v4 = fmaxf(fmaf(bflo(u.z), sc[4], sh2[4]), 0.f);
            float v5 = fmaxf(fmaf(bfhi(u.z), sc[5], sh2[5]), 0.f);
            float v6 = fmaxf(fmaf(bflo(u.w), sc[6], sh2[6]), 0.f);
            float v7 = fmaxf(fmaf(bfhi(u.w), sc[7], sh2[7]), 0.f);
            uint4 o;
            o.x = packbf2(v0, v1); o.y = packbf2(v2, v3);
            o.z = packbf2(v4, v5); o.w = packbf2(v6, v7);
            XsU[row * 16 + (tc ^ (row & 7))] = o;
        }
        __syncthreads();

        f32x4 acc[3];
#pragma unroll
        for (int n = 0; n < 3; ++n)
#pragma unroll
            for (int r2 = 0; r2 < 4; ++r2) acc[n][r2] = 0.f;

#pragma unroll
        for (int kt = 0; kt < 4; ++kt) {
            int row = w * 16 + lr;
            bf16x8 A = *(const bf16x8*)&XsU[row * 16 + ((kt * 4 + q) ^ (row & 7))];
#pragma unroll
            for (int n = 0; n < 3; ++n)
                acc[n] = __builtin_amdgcn_mfma_f32_16x16x32_bf16(A, Bf[kt][n], acc[n], 0, 0, 0);
        }
        __syncthreads();

        float dv[4];
#pragma unroll
        for (int r = 0; r < 4; ++r) dv[r] = dinv[row0 + w * 16 + q * 4 + r];
#pragma unroll
        for (int n = 0; n < 3; ++n) {
            int col = n * 16 + lr;
#pragma unroll
            for (int r = 0; r < 4; ++r) {
                int row = w * 16 + q * 4 + r;
                Xs[row * 128 + (((col >> 3) ^ (row & 7)) << 3) + (col & 7)] = f2bf(acc[n][r] * dv[r]);
            }
        }
        __syncthreads();
        for (int i = t; i < 384; i += 256) {
            int row = i / 6, cc = i - row * 6;
            ((uint4*)&H3[(size_t)(row0 + row) * 64])[cc] = XsU[row * 16 + (cc ^ (row & 7))];
        }
    }
}

// ---------------- aggregation: 16-lane group/node, grid-stride, dup-tail loads ----------------

__global__ __launch_bounds__(256) void agg128_k(const uint4* __restrict__ Hb4, const int* __restrict__ offs,
                                                const int* __restrict__ csr, const float* __restrict__ dinv,
                                                const float* __restrict__ bias, uint4* __restrict__ Zb4,
                                                float* __restrict__ sums, int n) {
    const int t = threadIdx.x;
    const int g16 = t >> 4;
    const int l16 = t & 15;
    float bs[8];
#pragma unroll
    for (int j = 0; j < 8; ++j) bs[j] = bias[l16 * 8 + j];
    float s[8] = {0.f,0.f,0.f,0.f,0.f,0.f,0.f,0.f};
    float qq[8] = {0.f,0.f,0.f,0.f,0.f,0.f,0.f,0.f};

    for (int node = blockIdx.x * 16 + g16; node < n; node += gridDim.x * 16) {
        int beg = offs[node], end = offs[node + 1];
        uint4 u = Hb4[(size_t)node * 16 + l16];
        float a[8];
        a[0] = bflo(u.x); a[1] = bfhi(u.x); a[2] = bflo(u.y); a[3] = bfhi(u.y);
        a[4] = bflo(u.z); a[5] = bfhi(u.z); a[6] = bflo(u.w); a[7] = bfhi(u.w);
        for (int e = beg; e < end; e += 8) {
            int rem = end - e;
            int s0 = csr[e];
            int s1 = (rem > 1) ? csr[e + 1] : s0;
            int s2 = (rem > 2) ? csr[e + 2] : s0;
            int s3 = (rem > 3) ? csr[e + 3] : s0;
            int s4 = (rem > 4) ? csr[e + 4] : s0;
            int s5 = (rem > 5) ? csr[e + 5] : s0;
            int s6 = (rem > 6) ? csr[e + 6] : s0;
            int s7 = (rem > 7) ? csr[e + 7] : s0;
            uint4 v0 = Hb4[(size_t)s0 * 16 + l16];
            uint4 v1 = Hb4[(size_t)s1 * 16 + l16];
            uint4 v2 = Hb4[(size_t)s2 * 16 + l16];
            uint4 v3 = Hb4[(size_t)s3 * 16 + l16];
            uint4 v4 = Hb4[(size_t)s4 * 16 + l16];
            uint4 v5 = Hb4[(size_t)s5 * 16 + l16];
            uint4 v6 = Hb4[(size_t)s6 * 16 + l16];
            uint4 v7 = Hb4[(size_t)s7 * 16 + l16];
#define ACC8(v) { a[0]+=bflo(v.x); a[1]+=bfhi(v.x); a[2]+=bflo(v.y); a[3]+=bfhi(v.y); \
                  a[4]+=bflo(v.z); a[5]+=bfhi(v.z); a[6]+=bflo(v.w); a[7]+=bfhi(v.w); }
            ACC8(v0);
            if (rem > 1) ACC8(v1);
            if (rem > 2) ACC8(v2);
            if (rem > 3) ACC8(v3);
            if (rem > 4) ACC8(v4);
            if (rem > 5) ACC8(v5);
            if (rem > 6) ACC8(v6);
            if (rem > 7) ACC8(v7);
#undef ACC8
        }
        float dv = dinv[node];
        float z[8];
#pragma unroll
        for (int j = 0; j < 8; ++j) {
            z[j] = fmaf(a[j], dv, bs[j]);
            s[j] += z[j];
            qq[j] += z[j] * z[j];
        }
        uint4 o;
        o.x = packbf2(z[0], z[1]); o.y = packbf2(z[2], z[3]);
        o.z = packbf2(z[4], z[5]); o.w = packbf2(z[6], z[7]);
        Zb4[(size_t)node * 16 + l16] = o;
    }

    __shared__ float red[2][16][128];
#pragma unroll
    for (int j = 0; j < 8; ++j) {
        red[0][g16][l16 * 8 + j] = s[j];
        red[1][g16][l16 * 8 + j] = qq[j];
    }
    __syncthreads();
    int f = t & 127, which = t >> 7;
    float acc = 0.f;
#pragma unroll
    for (int G = 0; G < 16; ++G) acc += red[which][G][f];
    atomicAdd(&sums[which * 128 + f], acc);
}

// ---------------- layer-3 aggregation: 8-lane group/node, grid-stride, dup-tail loads ----------------

__global__ __launch_bounds__(256) void agg40_k(const uint4* __restrict__ H34, const int* __restrict__ offs,
                                               const int* __restrict__ csr, const float* __restrict__ dinv,
                                               const float* __restrict__ bias, float* __restrict__ out, int n) {
    const int t = threadIdx.x;
    const int g8 = t >> 3, l8 = t & 7;
    float bl[8];
#pragma unroll
    for (int j = 0; j < 8; ++j) {
        int fj = l8 * 8 + j;
        bl[j] = (fj < FOUT) ? bias[fj] : 0.f;
    }

    for (int node = blockIdx.x * 32 + g8; node < n; node += gridDim.x * 32) {
        int beg = offs[node], end = offs[node + 1];
        uint4 u = H34[(size_t)node * 8 + l8];
        float a[8];
        a[0]=bflo(u.x); a[1]=bfhi(u.x); a[2]=bflo(u.y); a[3]=bfhi(u.y);
        a[4]=bflo(u.z); a[5]=bfhi(u.z); a[6]=bflo(u.w); a[7]=bfhi(u.w);

        for (int e = beg; e < end; e += 8) {
            int rem = end - e;
            int s0 = csr[e];
            int s1 = (rem > 1) ? csr[e + 1] : s0;
            int s2 = (rem > 2) ? csr[e + 2] : s0;
            int s3 = (rem > 3) ? csr[e + 3] : s0;
            int s4 = (rem > 4) ? csr[e + 4] : s0;
            int s5 = (rem > 5) ? csr[e + 5] : s0;
            int s6 = (rem > 6) ? csr[e + 6] : s0;
            int s7 = (rem > 7) ? csr[e + 7] : s0;
            uint4 v0 = H34[(size_t)s0 * 8 + l8];
            uint4 v1 = H34[(size_t)s1 * 8 + l8];
            uint4 v2 = H34[(size_t)s2 * 8 + l8];
            uint4 v3 = H34[(size_t)s3 * 8 + l8];
            uint4 v4 = H34[(size_t)s4 * 8 + l8];
            uint4 v5 = H34[(size_t)s5 * 8 + l8];
            uint4 v6 = H34[(size_t)s6 * 8 + l8];
            uint4 v7 = H34[(size_t)s7 * 8 + l8];
#define ACC8(v) { a[0]+=bflo(v.x); a[1]+=bfhi(v.x); a[2]+=bflo(v.y); a[3]+=bfhi(v.y); \
                  a[4]+=bflo(v.z); a[5]+=bfhi(v.z); a[6]+=bflo(v.w); a[7]+=bfhi(v.w); }
            ACC8(v0);
            if (rem > 1) ACC8(v1);
            if (rem > 2) ACC8(v2);
            if (rem > 3) ACC8(v3);
            if (rem > 4) ACC8(v4);
            if (rem > 5) ACC8(v5);
            if (rem > 6) ACC8(v6);
            if (rem > 7) ACC8(v7);
#undef ACC8
        }

        float dv = dinv[node];
        float val[8];
        float m = -INFINITY;
#pragma unroll
        for (int j = 0; j < 8; ++j) {
            int fj = l8 * 8 + j;
            val[j] = (fj < FOUT) ? fmaf(a[j], dv, bl[j]) : -INFINITY;
            m = fmaxf(m, val[j]);
        }
#pragma unroll
        for (int o = 4; o > 0; o >>= 1) m = fmaxf(m, __shfl_xor(m, o, 8));
        float es = 0.f;
#pragma unroll
        for (int j = 0; j < 8; ++j) es += (l8 * 8 + j < FOUT) ? expf(val[j] - m) : 0.f;
#pragma unroll
        for (int o = 4; o > 0; o >>= 1) es += __shfl_xor(es, o, 8);
        float lse = m + logf(es);
        if (l8 < 5) {
            float4 o0 = make_float4(val[0]-lse, val[1]-lse, val[2]-lse, val[3]-lse);
            float4 o1 = make_float4(val[4]-lse, val[5]-lse, val[6]-lse, val[7]-lse);
            float* op = out + (size_t)node * FOUT + l8 * 8;
            *(float4*)op = o0;
            *(float4*)(op + 4) = o1;
        }
    }
}

// ---------------- launch ----------------

extern "C" void kernel_launch(void* const* d_in, const int* in_sizes, int n_in,
                              void* d_out, int out_size, void* d_ws, size_t ws_size,
                              hipStream_t stream) {
    const float* x   = (const float*)d_in[0];
    const int*   src = (const int*)d_in[1];
    const int*   dst = (const int*)d_in[2];
    const float* W1  = (const float*)d_in[3];
    const float* b1  = (const float*)d_in[4];
    const float* W2  = (const float*)d_in[5];
    const float* b2  = (const float*)d_in[6];
    const float* W3  = (const float*)d_in[7];
    const float* b3  = (const float*)d_in[8];
    const float* g1  = (const float*)d_in[9];
    const float* be1 = (const float*)d_in[10];
    const float* g2  = (const float*)d_in[11];
    const float* be2 = (const float*)d_in[12];

    const int N = in_sizes[0] / FEAT;
    const int E = in_sizes[1];
    const int Np = (N + 63) & ~63;
    const int ntiles = Np / 64;
    const float inv_n = 1.0f / (float)N;
    float* out = (float*)d_out;

    char* p = (char*)d_ws;
    auto alloc = [&](size_t bytes) {
        char* r = p;
        p += (bytes + 255) & ~(size_t)255;
        return r;
    };
    float* dinv   = (float*)alloc((size_t)Np * 4);
    int*   cnt    = (int*)alloc((size_t)N * 4);
    int*   offs   = (int*)alloc((size_t)(N + 1) * 4);
    int*   cursor = (int*)alloc((size_t)N * 4);
    int*   csr    = (int*)alloc((size_t)E * 4);
    int*   bsum   = (int*)alloc(1024);
    int*   boff   = (int*)alloc(1024);
    float* sums1  = (float*)alloc(1024);
    float* sums2  = (float*)alloc(1024);
    unsigned short* Wt1 = (unsigned short*)alloc(4 * 4 * 128 * 8 * 2);
    unsigned short* Wt2 = (unsigned short*)alloc(4 * 4 * 128 * 8 * 2);
    unsigned short* Wt3 = (unsigned short*)alloc(4 * 4 * 48 * 8 * 2);
    unsigned short* Hb  = (unsigned short*)alloc((size_t)Np * FEAT * 2);
    unsigned short* Zb  = (unsigned short*)alloc((size_t)Np * FEAT * 2);
    unsigned short* H3  = (unsigned short*)alloc((size_t)Np * 64 * 2);

    int nb = (N + 1023) / 1024;

    // CSR build: one cooperative kernel (zero+count+scan+fill+cursor+dinv)
    {
        const int* srcA = src; const int* dstA = dst;
        int nA = N, eA = E, nbA = nb;
        void* args[] = {(void*)&srcA, (void*)&dstA, (void*)&cnt, (void*)&offs, (void*)&cursor,
                        (void*)&dinv, (void*)&csr, (void*)&bsum, (void*)&boff,
                        (void*)&nA, (void*)&eA, (void*)&nbA};
        hipLaunchCooperativeKernel((void*)csr_build_k, dim3(1024), dim3(256), args, 0, stream);
    }
    castW_k<<<48, 256, 0, stream>>>(W1, W2, W3, Wt1, Wt2, Wt3, sums1, sums2);

    // Layer 1
    gemm128_k<0><<<768, 256, 0, stream>>>(x, Wt1, nullptr, nullptr, nullptr, 0.f, dinv, Hb, ntiles, N);
    agg128_k<<<2048, 256, 0, stream>>>((const uint4*)Hb, offs, csr, dinv, b1, (uint4*)Zb, sums1, N);

    // Layer 2 (BN1+ReLU fused into staging, scale/shift computed inline from sums1)
    gemm128_k<1><<<768, 256, 0, stream>>>(Zb, Wt2, sums1, g1, be1, inv_n, dinv, Hb, ntiles, N);
    agg128_k<<<2048, 256, 0, stream>>>((const uint4*)Hb, offs, csr, dinv, b2, (uint4*)Zb, sums2, N);

    // Layer 3 (BN2+ReLU fused into staging) + log_softmax
    gemm40_k<<<1024, 256, 0, stream>>>(Zb, Wt3, sums2, g2, be2, inv_n, dinv, H3, ntiles);
    agg40_k<<<2048, 256, 0, stream>>>((const uint4*)H3, offs, csr, dinv, b3, out, N);
}

// Round 12
// 293.386 us; speedup vs baseline: 2.5968x; 2.5968x over previous
//
#include <hip/hip_runtime.h>
#include <cstdint>
#include <cstddef>

#define FEAT 128
#define FOUT 40
constexpr float BN_EPS = 1e-5f;

typedef __attribute__((ext_vector_type(8))) short bf16x8;
typedef __attribute__((ext_vector_type(4))) float f32x4;

__device__ __forceinline__ unsigned short f2bf(float f) {
    unsigned u = __float_as_uint(f);
    u += 0x7FFFu + ((u >> 16) & 1u);
    return (unsigned short)(u >> 16);
}
__device__ __forceinline__ float bflo(unsigned u) { return __uint_as_float(u << 16); }
__device__ __forceinline__ float bfhi(unsigned u) { return __uint_as_float(u & 0xFFFF0000u); }
__device__ __forceinline__ unsigned packbf2(float a, float b) {
    return (unsigned)f2bf(a) | ((unsigned)f2bf(b) << 16);
}

// ---------------- CSR build (separate kernels — cooperative grid.sync costs ~100us/sync on 8-XCD MI355X, R11 lesson) ----------------

__global__ __launch_bounds__(256) void count_k(const int* __restrict__ dst, int* __restrict__ cnt, int E) {
    int e = blockIdx.x * 256 + threadIdx.x;
    if (e < E) atomicAdd(&cnt[dst[e]], 1);
}

__global__ __launch_bounds__(256) void scan1_k(const int* __restrict__ cnt, int* __restrict__ bsum, int n) {
    __shared__ int sh[256];
    int base = blockIdx.x * 1024, t = threadIdx.x;
    int s = 0;
#pragma unroll
    for (int j = 0; j < 4; ++j) {
        int idx = base + t * 4 + j;
        if (idx < n) s += cnt[idx];
    }
    sh[t] = s;
    __syncthreads();
    for (int o = 128; o > 0; o >>= 1) {
        if (t < o) sh[t] += sh[t + o];
        __syncthreads();
    }
    if (t == 0) bsum[blockIdx.x] = sh[0];
}

__global__ void scan2_k(const int* __restrict__ bsum, int* __restrict__ boff, int nb,
                        int* __restrict__ offs, int n, int E) {
    __shared__ int sh[256];
    int t = threadIdx.x;
    if (nb <= 256) {
        int v = (t < nb) ? bsum[t] : 0;
        sh[t] = v;
        __syncthreads();
        for (int o = 1; o < 256; o <<= 1) {
            int x = (t >= o) ? sh[t - o] : 0;
            __syncthreads();
            sh[t] += x;
            __syncthreads();
        }
        if (t < nb) boff[t] = sh[t] - v;
        if (t == 0) offs[n] = E;
    } else if (t == 0) {
        int run = 0;
        for (int i = 0; i < nb; ++i) { boff[i] = run; run += bsum[i]; }
        offs[n] = E;
    }
}

// scan3 also emits cursor and dinv
__global__ __launch_bounds__(256) void scan3_k(const int* __restrict__ cnt, const int* __restrict__ boff,
                                               int* __restrict__ offs, int* __restrict__ cursor,
                                               float* __restrict__ dinv, int n) {
    __shared__ int sh[256];
    int base = blockIdx.x * 1024, t = threadIdx.x;
    int c[4];
    int s = 0;
#pragma unroll
    for (int j = 0; j < 4; ++j) {
        int idx = base + t * 4 + j;
        c[j] = (idx < n) ? cnt[idx] : 0;
        s += c[j];
    }
    sh[t] = s;
    __syncthreads();
    for (int o = 1; o < 256; o <<= 1) {
        int v = (t >= o) ? sh[t - o] : 0;
        __syncthreads();
        sh[t] += v;
        __syncthreads();
    }
    int g = boff[blockIdx.x] + sh[t] - s;
#pragma unroll
    for (int j = 0; j < 4; ++j) {
        int idx = base + t * 4 + j;
        if (idx < n) {
            offs[idx] = g;
            cursor[idx] = g;
            dinv[idx] = rsqrtf((float)(c[j] + 1));
        }
        g += c[j];
    }
}

__global__ __launch_bounds__(256) void fill_k(const int* __restrict__ src, const int* __restrict__ dst,
                                              int* __restrict__ cursor, int* __restrict__ csr, int E) {
    int e = blockIdx.x * 256 + threadIdx.x;
    if (e < E) {
        int d = dst[e];
        int p = atomicAdd(&cursor[d], 1);
        csr[p] = src[e];
    }
}

// ---------------- weight pack (+ zero both BN sums buffers) ----------------

__global__ __launch_bounds__(256) void castW_k(const float* __restrict__ W1, const float* __restrict__ W2,
                                               const float* __restrict__ W3,
                                               unsigned short* __restrict__ Wt1, unsigned short* __restrict__ Wt2,
                                               unsigned short* __restrict__ Wt3,
                                               float* __restrict__ sums1, float* __restrict__ sums2) {
    int tid = blockIdx.x * 256 + threadIdx.x;
    int stride = gridDim.x * 256;
    if (tid < 256) { sums1[tid] = 0.f; sums2[tid] = 0.f; }
    for (int i = tid; i < 4 * 4 * 128 * 8; i += stride) {
        int j = i & 7, c = (i >> 3) & 127, q = (i >> 10) & 3, kt = i >> 12;
        int k = kt * 32 + q * 8 + j;
        Wt1[i] = f2bf(W1[k * 128 + c]);
        Wt2[i] = f2bf(W2[k * 128 + c]);
    }
    for (int i = tid; i < 4 * 4 * 48 * 8; i += stride) {
        int j = i & 7, rest = i >> 3;
        int c = rest % 48, kq = rest / 48;
        int q = kq & 3, kt = kq >> 2;
        int k = kt * 32 + q * 8 + j;
        Wt3[i] = (c < FOUT) ? f2bf(W3[k * FOUT + c]) : (unsigned short)0;
    }
}

// ---------------- MFMA GEMM 128x128, BN computed inline from raw sums ----------------

template <int SRC>
__global__ __launch_bounds__(256, 3) void gemm128_k(const void* __restrict__ srcp,
                                                    const unsigned short* __restrict__ Wt,
                                                    const float* __restrict__ sums,
                                                    const float* __restrict__ gam,
                                                    const float* __restrict__ bet,
                                                    float inv_n,
                                                    const float* __restrict__ dinv,
                                                    unsigned short* __restrict__ Hb,
                                                    int ntiles, int nreal) {
    __shared__ uint4 XsU[64 * 16];
    unsigned short* Xs = (unsigned short*)XsU;

    const int t = threadIdx.x;
    const int tc = t & 15;
    const int l = t & 63, w = t >> 6;
    const int wm = w >> 1, wn = w & 1;
    const int lr = l & 15, q = l >> 4;

    float sc[8], sh2[8];
    if (SRC == 1) {
#pragma unroll
        for (int j = 0; j < 8; ++j) {
            int f = tc * 8 + j;
            float mu = sums[f] * inv_n;
            float var = sums[128 + f] * inv_n - mu * mu;
            float rstd = rsqrtf(var + BN_EPS);
            float scv = gam[f] * rstd;
            sc[j] = scv;
            sh2[j] = bet[f] - mu * scv;
        }
    }

    bf16x8 Bf[4][4];
#pragma unroll
    for (int kt = 0; kt < 4; ++kt)
#pragma unroll
        for (int n = 0; n < 4; ++n) {
            int col = wn * 64 + n * 16 + lr;
            Bf[kt][n] = *(const bf16x8*)&((const uint4*)Wt)[(kt * 4 + q) * 128 + col];
        }

    for (int tile = blockIdx.x; tile < ntiles; tile += gridDim.x) {
        const int row0 = tile * 64;
        __syncthreads();
#pragma unroll
        for (int k2 = 0; k2 < 4; ++k2) {
            int row = (t >> 4) + k2 * 16;
            int grow = row0 + row;
            uint4 o;
            if (SRC == 0) {
                if (grow < nreal) {
                    const float4* xp = (const float4*)((const float*)srcp + (size_t)grow * FEAT + tc * 8);
                    float4 f0 = xp[0], f1 = xp[1];
                    o.x = packbf2(f0.x, f0.y); o.y = packbf2(f0.z, f0.w);
                    o.z = packbf2(f1.x, f1.y); o.w = packbf2(f1.z, f1.w);
                } else {
                    o.x = 0u; o.y = 0u; o.z = 0u; o.w = 0u;
                }
            } else {
                uint4 u = ((const uint4*)((const unsigned short*)srcp + (size_t)grow * FEAT))[tc];
                float v0 = fmaxf(fmaf(bflo(u.x), sc[0], sh2[0]), 0.f);
                float v1 = fmaxf(fmaf(bfhi(u.x), sc[1], sh2[1]), 0.f);
                float v2 = fmaxf(fmaf(bflo(u.y), sc[2], sh2[2]), 0.f);
                float v3 = fmaxf(fmaf(bfhi(u.y), sc[3], sh2[3]), 0.f);
                float v4 = fmaxf(fmaf(bflo(u.z), sc[4], sh2[4]), 0.f);
                float v5 = fmaxf(fmaf(bfhi(u.z), sc[5], sh2[5]), 0.f);
                float v6 = fmaxf(fmaf(bflo(u.w), sc[6], sh2[6]), 0.f);
                float v7 = fmaxf(fmaf(bfhi(u.w), sc[7], sh2[7]), 0.f);
                o.x = packbf2(v0, v1); o.y = packbf2(v2, v3);
                o.z = packbf2(v4, v5); o.w = packbf2(v6, v7);
            }
            XsU[row * 16 + (tc ^ (row & 7))] = o;
        }
        __syncthreads();

        f32x4 acc[2][4];
#pragma unroll
        for (int m = 0; m < 2; ++m)
#pragma unroll
            for (int n = 0; n < 4; ++n)
#pragma unroll
                for (int r2 = 0; r2 < 4; ++r2) acc[m][n][r2] = 0.f;

#pragma unroll
        for (int kt = 0; kt < 4; ++kt) {
            int rowA = wm * 32 + lr;
            bf16x8 A0 = *(const bf16x8*)&XsU[rowA * 16 + ((kt * 4 + q) ^ (rowA & 7))];
            int rowB = rowA + 16;
            bf16x8 A1 = *(const bf16x8*)&XsU[rowB * 16 + ((kt * 4 + q) ^ (rowB & 7))];
#pragma unroll
            for (int n = 0; n < 4; ++n) {
                acc[0][n] = __builtin_amdgcn_mfma_f32_16x16x32_bf16(A0, Bf[kt][n], acc[0][n], 0, 0, 0);
                acc[1][n] = __builtin_amdgcn_mfma_f32_16x16x32_bf16(A1, Bf[kt][n], acc[1][n], 0, 0, 0);
            }
        }
        __syncthreads();

#pragma unroll
        for (int m = 0; m < 2; ++m) {
            float dv[4];
#pragma unroll
            for (int r = 0; r < 4; ++r) dv[r] = dinv[row0 + wm * 32 + m * 16 + q * 4 + r];
#pragma unroll
            for (int n = 0; n < 4; ++n) {
                int col = wn * 64 + n * 16 + lr;
#pragma unroll
                for (int r = 0; r < 4; ++r) {
                    int row = wm * 32 + m * 16 + q * 4 + r;
                    Xs[row * 128 + (((col >> 3) ^ (row & 7)) << 3) + (col & 7)] = f2bf(acc[m][n][r] * dv[r]);
                }
            }
        }
        __syncthreads();
#pragma unroll
        for (int k2 = 0; k2 < 4; ++k2) {
            int row = (t >> 4) + k2 * 16;
            ((uint4*)&Hb[(size_t)(row0 + row) * FEAT])[tc] = XsU[row * 16 + (tc ^ (row & 7))];
        }
    }
}

// ---------------- MFMA GEMM 128x40 (padded to 48), BN inline ----------------

__global__ __launch_bounds__(256, 4) void gemm40_k(const unsigned short* __restrict__ srcp,
                                                   const unsigned short* __restrict__ Wt,
                                                   const float* __restrict__ sums,
                                                   const float* __restrict__ gam,
                                                   const float* __restrict__ bet,
                                                   float inv_n,
                                                   const float* __restrict__ dinv,
                                                   unsigned short* __restrict__ H3,
                                                   int ntiles) {
    __shared__ uint4 XsU[64 * 16];
    unsigned short* Xs = (unsigned short*)XsU;
    const int t = threadIdx.x, tc = t & 15;
    const int l = t & 63, w = t >> 6, lr = l & 15, q = l >> 4;

    float sc[8], sh2[8];
#pragma unroll
    for (int j = 0; j < 8; ++j) {
        int f = tc * 8 + j;
        float mu = sums[f] * inv_n;
        float var = sums[128 + f] * inv_n - mu * mu;
        float rstd = rsqrtf(var + BN_EPS);
        float scv = gam[f] * rstd;
        sc[j] = scv;
        sh2[j] = bet[f] - mu * scv;
    }

    bf16x8 Bf[4][3];
#pragma unroll
    for (int kt = 0; kt < 4; ++kt)
#pragma unroll
        for (int n = 0; n < 3; ++n)
            Bf[kt][n] = *(const bf16x8*)&((const uint4*)Wt)[(kt * 4 + q) * 48 + n * 16 + lr];

    for (int tile = blockIdx.x; tile < ntiles; tile += gridDim.x) {
        const int row0 = tile * 64;
        __syncthreads();
#pragma unroll
        for (int k2 = 0; k2 < 4; ++k2) {
            int row = (t >> 4) + k2 * 16;
            int grow = row0 + row;
            uint4 u = ((const uint4*)(srcp + (size_t)grow * FEAT))[tc];
            float v0 = fmaxf(fmaf(bflo(u.x), sc[0], sh2[0]), 0.f);
            float v1 = fmaxf(fmaf(bfhi(u.x), sc[1], sh2[1]), 0.f);
            float v2 = fmaxf(fmaf(bflo(u.y), sc[2], sh2[2]), 0.f);
            float v3 = fmaxf(fmaf(bfhi(u.y), sc[3], sh2[3]), 0.f);
            float v4 = fmaxf(fmaf(bflo(u.z), sc[4], sh2[4]), 0.f);
            float v5 = fmaxf(fmaf(bfhi(u.z), sc[5], sh2[5]), 0.f);
            float v6 = fmaxf(fmaf(bflo(u.w), sc[6], sh2[6]), 0.f);
            float v7 = fmaxf(fmaf(bfhi(u.w), sc[7], sh2[7]), 0.f);
            uint4 o;
            o.x = packbf2(v0, v1); o.y = packbf2(v2, v3);
            o.z = packbf2(v4, v5); o.w = packbf2(v6, v7);
            XsU[row * 16 + (tc ^ (row & 7))] = o;
        }
        __syncthreads();

        f32x4 acc[3];
#pragma unroll
        for (int n = 0; n < 3; ++n)
#pragma unroll
            for (int r2 = 0; r2 < 4; ++r2) acc[n][r2] = 0.f;

#pragma unroll
        for (int kt = 0; kt < 4; ++kt) {
            int row = w * 16 + lr;
            bf16x8 A = *(const bf16x8*)&XsU[row * 16 + ((kt * 4 + q) ^ (row & 7))];
#pragma unroll
            for (int n = 0; n < 3; ++n)
                acc[n] = __builtin_amdgcn_mfma_f32_16x16x32_bf16(A, Bf[kt][n], acc[n], 0, 0, 0);
        }
        __syncthreads();

        float dv[4];
#pragma unroll
        for (int r = 0; r < 4; ++r) dv[r] = dinv[row0 + w * 16 + q * 4 + r];
#pragma unroll
        for (int n = 0; n < 3; ++n) {
            int col = n * 16 + lr;
#pragma unroll
            for (int r = 0; r < 4; ++r) {
                int row = w * 16 + q * 4 + r;
                Xs[row * 128 + (((col >> 3) ^ (row & 7)) << 3) + (col & 7)] = f2bf(acc[n][r] * dv[r]);
            }
        }
        __syncthreads();
        for (int i = t; i < 384; i += 256) {
            int row = i / 6, cc = i - row * 6;
            ((uint4*)&H3[(size_t)(row0 + row) * 64])[cc] = XsU[row * 16 + (cc ^ (row & 7))];
        }
    }
}

// ---------------- aggregation: 16-lane group/node, grid-stride, dup-tail loads ----------------

__global__ __launch_bounds__(256) void agg128_k(const uint4* __restrict__ Hb4, const int* __restrict__ offs,
                                                const int* __restrict__ csr, const float* __restrict__ dinv,
                                                const float* __restrict__ bias, uint4* __restrict__ Zb4,
                                                float* __restrict__ sums, int n) {
    const int t = threadIdx.x;
    const int g16 = t >> 4;
    const int l16 = t & 15;
    float bs[8];
#pragma unroll
    for (int j = 0; j < 8; ++j) bs[j] = bias[l16 * 8 + j];
    float s[8] = {0.f,0.f,0.f,0.f,0.f,0.f,0.f,0.f};
    float qq[8] = {0.f,0.f,0.f,0.f,0.f,0.f,0.f,0.f};

    for (int node = blockIdx.x * 16 + g16; node < n; node += gridDim.x * 16) {
        int beg = offs[node], end = offs[node + 1];
        uint4 u = Hb4[(size_t)node * 16 + l16];
        float a[8];
        a[0] = bflo(u.x); a[1] = bfhi(u.x); a[2] = bflo(u.y); a[3] = bfhi(u.y);
        a[4] = bflo(u.z); a[5] = bfhi(u.z); a[6] = bflo(u.w); a[7] = bfhi(u.w);
        for (int e = beg; e < end; e += 8) {
            int rem = end - e;
            int s0 = csr[e];
            int s1 = (rem > 1) ? csr[e + 1] : s0;
            int s2 = (rem > 2) ? csr[e + 2] : s0;
            int s3 = (rem > 3) ? csr[e + 3] : s0;
            int s4 = (rem > 4) ? csr[e + 4] : s0;
            int s5 = (rem > 5) ? csr[e + 5] : s0;
            int s6 = (rem > 6) ? csr[e + 6] : s0;
            int s7 = (rem > 7) ? csr[e + 7] : s0;
            uint4 v0 = Hb4[(size_t)s0 * 16 + l16];
            uint4 v1 = Hb4[(size_t)s1 * 16 + l16];
            uint4 v2 = Hb4[(size_t)s2 * 16 + l16];
            uint4 v3 = Hb4[(size_t)s3 * 16 + l16];
            uint4 v4 = Hb4[(size_t)s4 * 16 + l16];
            uint4 v5 = Hb4[(size_t)s5 * 16 + l16];
            uint4 v6 = Hb4[(size_t)s6 * 16 + l16];
            uint4 v7 = Hb4[(size_t)s7 * 16 + l16];
#define ACC8(v) { a[0]+=bflo(v.x); a[1]+=bfhi(v.x); a[2]+=bflo(v.y); a[3]+=bfhi(v.y); \
                  a[4]+=bflo(v.z); a[5]+=bfhi(v.z); a[6]+=bflo(v.w); a[7]+=bfhi(v.w); }
            ACC8(v0);
            if (rem > 1) ACC8(v1);
            if (rem > 2) ACC8(v2);
            if (rem > 3) ACC8(v3);
            if (rem > 4) ACC8(v4);
            if (rem > 5) ACC8(v5);
            if (rem > 6) ACC8(v6);
            if (rem > 7) ACC8(v7);
#undef ACC8
        }
        float dv = dinv[node];
        float z[8];
#pragma unroll
        for (int j = 0; j < 8; ++j) {
            z[j] = fmaf(a[j], dv, bs[j]);
            s[j] += z[j];
            qq[j] += z[j] * z[j];
        }
        uint4 o;
        o.x = packbf2(z[0], z[1]); o.y = packbf2(z[2], z[3]);
        o.z = packbf2(z[4], z[5]); o.w = packbf2(z[6], z[7]);
        Zb4[(size_t)node * 16 + l16] = o;
    }

    __shared__ float red[2][16][128];
#pragma unroll
    for (int j = 0; j < 8; ++j) {
        red[0][g16][l16 * 8 + j] = s[j];
        red[1][g16][l16 * 8 + j] = qq[j];
    }
    __syncthreads();
    int f = t & 127, which = t >> 7;
    float acc = 0.f;
#pragma unroll
    for (int G = 0; G < 16; ++G) acc += red[which][G][f];
    atomicAdd(&sums[which * 128 + f], acc);
}

// ---------------- layer-3 aggregation: 8-lane group/node, grid-stride, dup-tail loads ----------------

__global__ __launch_bounds__(256) void agg40_k(const uint4* __restrict__ H34, const int* __restrict__ offs,
                                               const int* __restrict__ csr, const float* __restrict__ dinv,
                                               const float* __restrict__ bias, float* __restrict__ out, int n) {
    const int t = threadIdx.x;
    const int g8 = t >> 3, l8 = t & 7;
    float bl[8];
#pragma unroll
    for (int j = 0; j < 8; ++j) {
        int fj = l8 * 8 + j;
        bl[j] = (fj < FOUT) ? bias[fj] : 0.f;
    }

    for (int node = blockIdx.x * 32 + g8; node < n; node += gridDim.x * 32) {
        int beg = offs[node], end = offs[node + 1];
        uint4 u = H34[(size_t)node * 8 + l8];
        float a[8];
        a[0]=bflo(u.x); a[1]=bfhi(u.x); a[2]=bflo(u.y); a[3]=bfhi(u.y);
        a[4]=bflo(u.z); a[5]=bfhi(u.z); a[6]=bflo(u.w); a[7]=bfhi(u.w);

        for (int e = beg; e < end; e += 8) {
            int rem = end - e;
            int s0 = csr[e];
            int s1 = (rem > 1) ? csr[e + 1] : s0;
            int s2 = (rem > 2) ? csr[e + 2] : s0;
            int s3 = (rem > 3) ? csr[e + 3] : s0;
            int s4 = (rem > 4) ? csr[e + 4] : s0;
            int s5 = (rem > 5) ? csr[e + 5] : s0;
            int s6 = (rem > 6) ? csr[e + 6] : s0;
            int s7 = (rem > 7) ? csr[e + 7] : s0;
            uint4 v0 = H34[(size_t)s0 * 8 + l8];
            uint4 v1 = H34[(size_t)s1 * 8 + l8];
            uint4 v2 = H34[(size_t)s2 * 8 + l8];
            uint4 v3 = H34[(size_t)s3 * 8 + l8];
            uint4 v4 = H34[(size_t)s4 * 8 + l8];
            uint4 v5 = H34[(size_t)s5 * 8 + l8];
            uint4 v6 = H34[(size_t)s6 * 8 + l8];
            uint4 v7 = H34[(size_t)s7 * 8 + l8];
#define ACC8(v) { a[0]+=bflo(v.x); a[1]+=bfhi(v.x); a[2]+=bflo(v.y); a[3]+=bfhi(v.y); \
                  a[4]+=bflo(v.z); a[5]+=bfhi(v.z); a[6]+=bflo(v.w); a[7]+=bfhi(v.w); }
            ACC8(v0);
            if (rem > 1) ACC8(v1);
            if (rem > 2) ACC8(v2);
            if (rem > 3) ACC8(v3);
            if (rem > 4) ACC8(v4);
            if (rem > 5) ACC8(v5);
            if (rem > 6) ACC8(v6);
            if (rem > 7) ACC8(v7);
#undef ACC8
        }

        float dv = dinv[node];
        float val[8];
        float m = -INFINITY;
#pragma unroll
        for (int j = 0; j < 8; ++j) {
            int fj = l8 * 8 + j;
            val[j] = (fj < FOUT) ? fmaf(a[j], dv, bl[j]) : -INFINITY;
            m = fmaxf(m, val[j]);
        }
#pragma unroll
        for (int o = 4; o > 0; o >>= 1) m = fmaxf(m, __shfl_xor(m, o, 8));
        float es = 0.f;
#pragma unroll
        for (int j = 0; j < 8; ++j) es += (l8 * 8 + j < FOUT) ? expf(val[j] - m) : 0.f;
#pragma unroll
        for (int o = 4; o > 0; o >>= 1) es += __shfl_xor(es, o, 8);
        float lse = m + logf(es);
        if (l8 < 5) {
            float4 o0 = make_float4(val[0]-lse, val[1]-lse, val[2]-lse, val[3]-lse);
            float4 o1 = make_float4(val[4]-lse, val[5]-lse, val[6]-lse, val[7]-lse);
            float* op = out + (size_t)node * FOUT + l8 * 8;
            *(float4*)op = o0;
            *(float4*)(op + 4) = o1;
        }
    }
}

// ---------------- launch ----------------

extern "C" void kernel_launch(void* const* d_in, const int* in_sizes, int n_in,
                              void* d_out, int out_size, void* d_ws, size_t ws_size,
                              hipStream_t stream) {
    const float* x   = (const float*)d_in[0];
    const int*   src = (const int*)d_in[1];
    const int*   dst = (const int*)d_in[2];
    const float* W1  = (const float*)d_in[3];
    const float* b1  = (const float*)d_in[4];
    const float* W2  = (const float*)d_in[5];
    const float* b2  = (const float*)d_in[6];
    const float* W3  = (const float*)d_in[7];
    const float* b3  = (const float*)d_in[8];
    const float* g1  = (const float*)d_in[9];
    const float* be1 = (const float*)d_in[10];
    const float* g2  = (const float*)d_in[11];
    const float* be2 = (const float*)d_in[12];

    const int N = in_sizes[0] / FEAT;
    const int E = in_sizes[1];
    const int Np = (N + 63) & ~63;
    const int ntiles = Np / 64;
    const float inv_n = 1.0f / (float)N;
    float* out = (float*)d_out;

    char* p = (char*)d_ws;
    auto alloc = [&](size_t bytes) {
        char* r = p;
        p += (bytes + 255) & ~(size_t)255;
        return r;
    };
    float* dinv   = (float*)alloc((size_t)Np * 4);
    int*   cnt    = (int*)alloc((size_t)N * 4);
    int*   offs   = (int*)alloc((size_t)(N + 1) * 4);
    int*   cursor = (int*)alloc((size_t)N * 4);
    int*   csr    = (int*)alloc((size_t)E * 4);
    int*   bsum   = (int*)alloc(1024);
    int*   boff   = (int*)alloc(1024);
    float* sums1  = (float*)alloc(1024);
    float* sums2  = (float*)alloc(1024);
    unsigned short* Wt1 = (unsigned short*)alloc(4 * 4 * 128 * 8 * 2);
    unsigned short* Wt2 = (unsigned short*)alloc(4 * 4 * 128 * 8 * 2);
    unsigned short* Wt3 = (unsigned short*)alloc(4 * 4 * 48 * 8 * 2);
    unsigned short* Hb  = (unsigned short*)alloc((size_t)Np * FEAT * 2);
    unsigned short* Zb  = (unsigned short*)alloc((size_t)Np * FEAT * 2);
    unsigned short* H3  = (unsigned short*)alloc((size_t)Np * 64 * 2);

    const int nb = (N + 1023) / 1024;
    const int eb = (E + 255) / 256;

    // CSR build + dinv (separate small kernels; R11 showed cooperative grid.sync is ~100us/sync here)
    hipMemsetAsync(cnt, 0, (size_t)N * 4, stream);
    count_k<<<eb, 256, 0, stream>>>(dst, cnt, E);
    scan1_k<<<nb, 256, 0, stream>>>(cnt, bsum, N);
    scan2_k<<<1, 256, 0, stream>>>(bsum, boff, nb, offs, N, E);
    scan3_k<<<nb, 256, 0, stream>>>(cnt, boff, offs, cursor, dinv, N);
    fill_k<<<eb, 256, 0, stream>>>(src, dst, cursor, csr, E);
    castW_k<<<48, 256, 0, stream>>>(W1, W2, W3, Wt1, Wt2, Wt3, sums1, sums2);

    // Layer 1
    gemm128_k<0><<<768, 256, 0, stream>>>(x, Wt1, nullptr, nullptr, nullptr, 0.f, dinv, Hb, ntiles, N);
    agg128_k<<<2048, 256, 0, stream>>>((const uint4*)Hb, offs, csr, dinv, b1, (uint4*)Zb, sums1, N);

    // Layer 2 (BN1+ReLU fused into staging, scale/shift computed inline from sums1)
    gemm128_k<1><<<768, 256, 0, stream>>>(Zb, Wt2, sums1, g1, be1, inv_n, dinv, Hb, ntiles, N);
    agg128_k<<<2048, 256, 0, stream>>>((const uint4*)Hb, offs, csr, dinv, b2, (uint4*)Zb, sums2, N);

    // Layer 3 (BN2+ReLU fused into staging) + log_softmax
    gemm40_k<<<1024, 256, 0, stream>>>(Zb, Wt3, sums2, g2, be2, inv_n, dinv, H3, ntiles);
    agg40_k<<<2048, 256, 0, stream>>>((const uint4*)H3, offs, csr, dinv, b3, out, N);
}